// Round 14
// baseline (115.875 us; speedup 1.0000x reference)
//
#include <hip/hip_runtime.h>
#include <stdint.h>

#define H 8
#define DH 96
#define L 2048
#define NB 2
#define D 768

typedef unsigned short u16;
typedef unsigned int u32;
typedef __attribute__((ext_vector_type(8))) __bf16 bf16x8;
typedef __attribute__((ext_vector_type(4))) float f32x4;
typedef __attribute__((ext_vector_type(4))) u32 u32x4;
typedef __attribute__((ext_vector_type(2))) u32 u32x2;
typedef __attribute__((ext_vector_type(4))) u16 u16x4;

// softmax scale folded with log2(e): 96^-0.5 * 1.4426950408889634
#define QSCALE 0.14724444f

static __device__ __forceinline__ u16 f2bf(float f) {
  union { __bf16 h; u16 u; } v;
  v.h = (__bf16)f;
  return v.u;
}

static __device__ __forceinline__ bf16x8 cvt8r(f32x4 a, f32x4 b) {
  bf16x8 r;
  r[0] = (__bf16)a[0]; r[1] = (__bf16)a[1]; r[2] = (__bf16)a[2]; r[3] = (__bf16)a[3];
  r[4] = (__bf16)b[0]; r[5] = (__bf16)b[1]; r[6] = (__bf16)b[2]; r[7] = (__bf16)b[3];
  return r;
}

// ---------------------------------------------------------------------------
// Fused QKV projection + RoPE (z=0: Q, z=1: K, z=2: V->V^T)
// 128x128 tile, 4 waves 64x64, BK=64: 12 K-steps (barrier drains halved vs
// BK=32) and the per-step compute phase (32 MFMA/wave) now EXCEEDS HBM
// latency, so the one step of slack the vmcnt(0)-draining barrier allows is
// sufficient. 1-deep reg prefetch, dbuf LDS (73.7 KB, 2 blocks/CU), one
// barrier per step. XCD swizzle for A-panel L2 reuse.
// ---------------------------------------------------------------------------
__global__ __launch_bounds__(256, 2)
void proj_qkv(const float* __restrict__ Qin, const float* __restrict__ Kin,
              const float* __restrict__ Vin,
              const float* __restrict__ Wq, const float* __restrict__ Wk,
              const float* __restrict__ Wv,
              const float* __restrict__ cq, const float* __restrict__ ck,
              u16* __restrict__ qo, u16* __restrict__ ko, u16* __restrict__ vo)
{
  __shared__ u16 a_lds[2][128 * 72];
  __shared__ u16 b_lds[2][128 * 72];
  const int tid = threadIdx.x;
  const int lane = tid & 63;
  const int w = tid >> 6;
  const int wr = w >> 1, wc = w & 1;
  const int fr = lane & 15;
  const int hi = lane >> 4;

  // swizzle: the 6 col-blocks of one (z, row-panel) share f%8 -> same XCD
  const int f = blockIdx.x;
  const int xr = f & 7;
  const int g = f >> 3;          // 0..71
  const int z = g / 24;
  const int gg = g % 24;
  const int by = xr + 8 * (gg & 3);   // 0..31
  const int bx = gg >> 2;             // 0..5
  const int row0 = by * 128;
  const int col0 = bx * 128;

  const float* A = (z == 0) ? Qin : ((z == 1) ? Kin : Vin);
  const float* W = (z == 0) ? Wq : ((z == 1) ? Wk : Wv);

  // staging map: 128x64 f32 per array per step; thread covers rows
  // {arow, arow+64}, cols acol..acol+15 -> 8 f32x4 each for A and W.
  const int arow = tid >> 2;
  const int acol = (tid & 3) * 16;
  const float* pA  = A + (size_t)(row0 + arow) * D + acol;
  const float* pA2 = pA + (size_t)64 * D;
  const float* pW  = W + (size_t)(col0 + arow) * D + acol;
  const float* pW2 = pW + (size_t)64 * D;

  f32x4 acc[4][4] = {};
  f32x4 Ra[8], Rb[8];

  auto issue = [&](int k) {
#pragma unroll
    for (int i = 0; i < 4; i++) {
      Ra[i]     = *(const f32x4*)(pA  + k + i * 4);
      Ra[i + 4] = *(const f32x4*)(pA2 + k + i * 4);
      Rb[i]     = *(const f32x4*)(pW  + k + i * 4);
      Rb[i + 4] = *(const f32x4*)(pW2 + k + i * 4);
    }
  };
  auto stage = [&](int bi) {
    *(bf16x8*)(&a_lds[bi][arow * 72 + acol])            = cvt8r(Ra[0], Ra[1]);
    *(bf16x8*)(&a_lds[bi][arow * 72 + acol + 8])        = cvt8r(Ra[2], Ra[3]);
    *(bf16x8*)(&a_lds[bi][(arow + 64) * 72 + acol])     = cvt8r(Ra[4], Ra[5]);
    *(bf16x8*)(&a_lds[bi][(arow + 64) * 72 + acol + 8]) = cvt8r(Ra[6], Ra[7]);
    *(bf16x8*)(&b_lds[bi][arow * 72 + acol])            = cvt8r(Rb[0], Rb[1]);
    *(bf16x8*)(&b_lds[bi][arow * 72 + acol + 8])        = cvt8r(Rb[2], Rb[3]);
    *(bf16x8*)(&b_lds[bi][(arow + 64) * 72 + acol])     = cvt8r(Rb[4], Rb[5]);
    *(bf16x8*)(&b_lds[bi][(arow + 64) * 72 + acol + 8]) = cvt8r(Rb[6], Rb[7]);
  };
  auto compute = [&](int bi) {
#pragma unroll
    for (int ks = 0; ks < 2; ks++) {
      bf16x8 af[4], bf[4];
#pragma unroll
      for (int m = 0; m < 4; m++)
        af[m] = *(const bf16x8*)(&a_lds[bi][(wr * 64 + m * 16 + fr) * 72 + ks * 32 + hi * 8]);
#pragma unroll
      for (int n = 0; n < 4; n++)
        bf[n] = *(const bf16x8*)(&b_lds[bi][(wc * 64 + n * 16 + fr) * 72 + ks * 32 + hi * 8]);
#pragma unroll
      for (int m = 0; m < 4; m++)
#pragma unroll
        for (int n = 0; n < 4; n++)
          acc[m][n] = __builtin_amdgcn_mfma_f32_16x16x32_bf16(af[m], bf[n], acc[m][n], 0, 0, 0);
    }
  };

  // prologue: tile0 -> buf0 (cold); tile1 -> R
  issue(0);
  stage(0);
  issue(64);
  __syncthreads();

  // 12 tiles of BK=64; one barrier per step; issue(j+2) after the barrier so
  // its loads get a full compute phase before the next drain.
#pragma unroll 1
  for (int jj = 0; jj < 6; jj++) {
    const int j = jj * 2;
    compute(0);                      // tile j
    stage(1);                        // tile j+1 (R issued 1 step ago)
    __syncthreads();
    if (j < 10) issue((j + 2) * 64); // tile j+2
    compute(1);                      // tile j+1
    if (j + 2 < 12) stage(0);        // tile j+2
    __syncthreads();
    if (j + 1 < 10) issue((j + 3) * 64); // tile j+3
  }

  if (z == 2) {
#pragma unroll
    for (int m = 0; m < 4; m++) {
      int rbase = row0 + wr * 64 + m * 16 + hi * 4;
#pragma unroll
      for (int n = 0; n < 4; n++) {
        int c = col0 + wc * 64 + n * 16 + fr;
        int hh = c / DH, dd = c % DH;
#pragma unroll
        for (int r = 0; r < 4; r++) {
          int row = rbase + r;
          int b = row >> 11, l = row & (L - 1);
          vo[((size_t)((b * H + hh) * DH + dd)) * L + l] = f2bf(acc[m][n][r]);
        }
      }
    }
  } else {
    // RoPE: partner (dd, dd+16) = fragments (n1, n1+1) at same lane.
    const float* coords = (z == 0) ? cq : ck;
    u16* outp = (z == 0) ? qo : ko;
    const float postscale = (z == 0) ? QSCALE : 1.0f;
#pragma unroll
    for (int m = 0; m < 4; m++) {
      int rbase = row0 + wr * 64 + m * 16 + hi * 4;
#pragma unroll
      for (int np = 0; np < 2; np++) {
        int n1 = np * 2;
        int c1 = col0 + wc * 64 + n1 * 16 + fr;
        int hh = c1 / DH;
        int dd1 = c1 % DH;
        int axis = dd1 / 32;
        int j = dd1 & 15;
        float invf = exp2f(-(float)j * 0.83048202372184058f);
#pragma unroll
        for (int r = 0; r < 4; r++) {
          int row = rbase + r;
          int b = row >> 11, l = row & (L - 1);
          float coord = coords[((size_t)(b * L + l)) * 3 + axis];
          float ang = coord * invf;
          float sn = __sinf(ang), cs = __cosf(ang);
          float x1 = acc[m][n1][r], x2 = acc[m][n1 + 1][r];
          size_t base = ((size_t)((b * H + hh) * L + l)) * DH;
          outp[base + dd1] = f2bf((x1 * cs - x2 * sn) * postscale);
          outp[base + dd1 + 16] = f2bf((x1 * sn + x2 * cs) * postscale);
        }
      }
    }
  }
}

// ---------------------------------------------------------------------------
// Flash attention: r9 structure (1-deep in-wave prefetch, dbuf LDS, ONE
// barrier/tile, defer-max, lane-local l) + XCD swizzle.  (unchanged)
// ---------------------------------------------------------------------------
#define KSTR 104
#define VSTR 72
#define NT   (L / 64)
__global__ __launch_bounds__(256, 2)
void attn_fwd(const u16* __restrict__ q_ws, const u16* __restrict__ k_ws,
              const u16* __restrict__ vt_ws, u16* __restrict__ ao)
{
  __shared__ u16 k_lds[2][64 * KSTR];
  __shared__ u16 vt_lds[2][96 * VSTR];
  const int tid = threadIdx.x;
  const int lane = tid & 63;
  const int w = tid >> 6;

  // swizzle: q-tiles of one bh share f%8 -> same XCD (K/V L2-resident)
  const int f = blockIdx.x;
  const int xr = f & 7;
  const int g = f >> 3;          // 0..63
  const int qx = g & 31;
  const int bh = xr + 8 * (g >> 5);
  const int q0 = qx * 64;

  const int fr = lane & 15;
  const int hi = lane >> 4;
  const int fko = hi * 8;

  // staging offsets (K natural; V^T columns sigma-permuted in 4-chunks)
  int kg_off[3], kl_off[3], vg_off[3], vl0_off[3], vl1_off[3];
#pragma unroll
  for (int it = 0; it < 3; it++) {
    int ch = tid + it * 256;
    int krow = ch / 12, koff = (ch % 12) * 8;
    kg_off[it] = krow * DH + koff;
    kl_off[it] = krow * KSTR + koff;
    int vrow = ch >> 3, vq = (ch & 7) * 2;
    vg_off[it] = vrow * L + vq * 4;
    int s0 = ((vq >> 3) << 5) | ((vq & 3) << 3) | (((vq >> 2) & 1) << 2);
    int vq1 = vq + 1;
    int s1 = ((vq1 >> 3) << 5) | ((vq1 & 3) << 3) | (((vq1 >> 2) & 1) << 2);
    vl0_off[it] = vrow * VSTR + s0;
    vl1_off[it] = vrow * VSTR + s1;
  }

  // Q fragments (B-operand: lane fr = q-row)
  bf16x8 qf[3];
  const u16* qbase = q_ws + ((size_t)bh * L + q0 + w * 16 + fr) * DH;
#pragma unroll
  for (int ks = 0; ks < 3; ks++)
    qf[ks] = *(const bf16x8*)(qbase + ks * 32 + fko);

  f32x4 o[6] = {};
  float m_r = -1e30f, l_r = 0.f;

  const u16* kbase = k_ws + (size_t)bh * L * DH;
  const u16* vtbase = vt_ws + (size_t)bh * DH * L;

  u32x4 kreg[3], vreg[3];
#pragma unroll
  for (int it = 0; it < 3; it++) {
    kreg[it] = *(const u32x4*)(kbase + kg_off[it]);
    vreg[it] = *(const u32x4*)(vtbase + vg_off[it]);
  }
#pragma unroll
  for (int it = 0; it < 3; it++) {
    *(u32x4*)(&k_lds[0][kl_off[it]]) = kreg[it];
    u32x2 lo = { vreg[it][0], vreg[it][1] };
    u32x2 hi2 = { vreg[it][2], vreg[it][3] };
    *(u32x2*)(&vt_lds[0][vl0_off[it]]) = lo;
    *(u32x2*)(&vt_lds[0][vl1_off[it]]) = hi2;
  }
  __syncthreads();

  int cur = 0;
  for (int t = 0; t < NT; t++) {
    if (t + 1 < NT) {  // in-wave prefetch; latency hides under compute
      const u16* kb = kbase + (size_t)(t + 1) * 64 * DH;
      const u16* vb = vtbase + (t + 1) * 64;
#pragma unroll
      for (int it = 0; it < 3; it++) {
        kreg[it] = *(const u32x4*)(kb + kg_off[it]);
        vreg[it] = *(const u32x4*)(vb + vg_off[it]);
      }
    }

    // S^T = K Q^T : lane fr = q, s[kf][reg] at k = kf*16+hi*4+reg
    f32x4 s[4] = {};
#pragma unroll
    for (int ks = 0; ks < 3; ks++)
#pragma unroll
      for (int kf = 0; kf < 4; kf++) {
        bf16x8 kfrag = *(const bf16x8*)(&k_lds[cur][(kf * 16 + fr) * KSTR + ks * 32 + fko]);
        s[kf] = __builtin_amdgcn_mfma_f32_16x16x32_bf16(kfrag, qf[ks], s[kf], 0, 0, 0);
      }

    // T13 defer-max
    float pmax = fmaxf(fmaxf(s[0][0], s[0][1]), fmaxf(s[0][2], s[0][3]));
#pragma unroll
    for (int kf = 1; kf < 4; kf++)
      pmax = fmaxf(pmax, fmaxf(fmaxf(s[kf][0], s[kf][1]), fmaxf(s[kf][2], s[kf][3])));
    if (!__all(pmax - m_r <= 8.0f)) {
      float mx = fmaxf(pmax, __shfl_xor(pmax, 16));
      mx = fmaxf(mx, __shfl_xor(mx, 32));
      float mn = fmaxf(m_r, mx);
      float alpha = exp2f(m_r - mn);
      m_r = mn;
      l_r *= alpha;
#pragma unroll
      for (int df = 0; df < 6; df++)
#pragma unroll
        for (int r = 0; r < 4; r++)
          o[df][r] *= alpha;
    }

    float p[4][4];
    float rs = 0.f;
#pragma unroll
    for (int kf = 0; kf < 4; kf++)
#pragma unroll
      for (int r = 0; r < 4; r++) {
        float pv = exp2f(s[kf][r] - m_r);
        p[kf][r] = pv;
        rs += pv;
      }
    l_r += rs;  // lane-local; reduced in epilogue

    bf16x8 pt[2];
#pragma unroll
    for (int ks = 0; ks < 2; ks++)
#pragma unroll
      for (int j = 0; j < 8; j++)
        pt[ks][j] = (__bf16)p[2 * ks + (j >> 2)][j & 3];

    // O^T += V P^T
#pragma unroll
    for (int ks = 0; ks < 2; ks++)
#pragma unroll
      for (int df = 0; df < 6; df++) {
        bf16x8 vfrag = *(const bf16x8*)(&vt_lds[cur][(df * 16 + fr) * VSTR + ks * 32 + fko]);
        o[df] = __builtin_amdgcn_mfma_f32_16x16x32_bf16(vfrag, pt[ks], o[df], 0, 0, 0);
      }

    if (t + 1 < NT) {  // write buf last read at t-1 (ordered by prev barrier)
#pragma unroll
      for (int it = 0; it < 3; it++) {
        *(u32x4*)(&k_lds[cur ^ 1][kl_off[it]]) = kreg[it];
        u32x2 lo = { vreg[it][0], vreg[it][1] };
        u32x2 hi2 = { vreg[it][2], vreg[it][3] };
        *(u32x2*)(&vt_lds[cur ^ 1][vl0_off[it]]) = lo;
        *(u32x2*)(&vt_lds[cur ^ 1][vl1_off[it]]) = hi2;
      }
      __syncthreads();
      cur ^= 1;
    }
  }

  // epilogue: reduce l across the 4 hi-lanes of each q-row, then store
  float l_tot = l_r + __shfl_xor(l_r, 16);
  l_tot += __shfl_xor(l_tot, 32);
  const int b = bh >> 3, hh = bh & 7;
  const int l = q0 + w * 16 + fr;
  const float inv = 1.f / l_tot;
  u16* aop = ao + ((size_t)(b * L + l)) * D + hh * DH + hi * 4;
#pragma unroll
  for (int df = 0; df < 6; df++) {
    u16x4 pk;
#pragma unroll
    for (int r = 0; r < 4; r++)
      pk[r] = f2bf(o[df][r] * inv);
    *(u16x4*)(aop + df * 16) = pk;
  }
}

// ---------------------------------------------------------------------------
// Output projection: out = AO @ Wo^T; 64x64 tiles, XCD swizzle, 2-deep
// prefetch + dbuf LDS, one barrier per K-step.  (unchanged)
// ---------------------------------------------------------------------------
__global__ __launch_bounds__(256, 2)
void gemm_out(const u16* __restrict__ A, const float* __restrict__ W,
              float* __restrict__ out)
{
  __shared__ u16 a_lds[2][64 * 40];
  __shared__ u16 b_lds[2][64 * 40];
  const int tid = threadIdx.x;
  const int lane = tid & 63;
  const int w = tid >> 6;
  const int wr = w >> 1, wc = w & 1;

  const int f = blockIdx.x;
  const int xr = f & 7;
  const int g = f >> 3;          // 0..95
  const int bx = g % 12;
  const int wq = g / 12;         // 0..7
  const int by = xr + 8 * wq;    // 0..63
  const int row0 = by * 64;
  const int col0 = bx * 64;

  f32x4 acc[2][2] = {};
  const int srow = tid >> 2;
  const int scol = (tid & 3) * 8;
  const u16* pA = A + (size_t)(row0 + srow) * D + scol;
  const float* pW = W + (size_t)(col0 + srow) * D + scol;
  const int fr = lane & 15;
  const int fk = (lane >> 4) * 8;

  auto issueG = [&](int k, u32x4* ra, f32x4* rb) {
    ra[0] = *(const u32x4*)(pA + k);
    rb[0] = *(const f32x4*)(pW + k);
    rb[1] = *(const f32x4*)(pW + k + 4);
  };
  auto writeG = [&](int bi, const u32x4* ra, const f32x4* rb) {
    *(u32x4*)(&a_lds[bi][srow * 40 + scol]) = ra[0];
    *(bf16x8*)(&b_lds[bi][srow * 40 + scol]) = cvt8r(rb[0], rb[1]);
  };
  auto computeG = [&](int bi) {
    bf16x8 af[2], bfr[2];
#pragma unroll
    for (int m = 0; m < 2; m++)
      af[m] = *(const bf16x8*)(&a_lds[bi][(wr * 32 + m * 16 + fr) * 40 + fk]);
#pragma unroll
    for (int n = 0; n < 2; n++)
      bfr[n] = *(const bf16x8*)(&b_lds[bi][(wc * 32 + n * 16 + fr) * 40 + fk]);
#pragma unroll
    for (int m = 0; m < 2; m++)
#pragma unroll
      for (int n = 0; n < 2; n++)
        acc[m][n] = __builtin_amdgcn_mfma_f32_16x16x32_bf16(af[m], bfr[n], acc[m][n], 0, 0, 0);
  };

  u32x4 raA[1], raB[1];
  f32x4 rbA[2], rbB[2];
  issueG(0, raB, rbB);
  writeG(0, raB, rbB);
  issueG(32, raA, rbA);
  __syncthreads();

  for (int k0 = 0; k0 < D; k0 += 64) {
    if (k0 + 64 < D) issueG(k0 + 64, raB, rbB);
    computeG(0);
    writeG(1, raA, rbA);
    __syncthreads();
    if (k0 + 96 < D) issueG(k0 + 96, raA, rbA);
    computeG(1);
    if (k0 + 64 < D) writeG(0, raB, rbB);
    __syncthreads();
  }

#pragma unroll
  for (int m = 0; m < 2; m++) {
    int rbase = row0 + wr * 32 + m * 16 + (lane >> 4) * 4;
#pragma unroll
    for (int n = 0; n < 2; n++) {
      int c = col0 + wc * 32 + n * 16 + fr;
#pragma unroll
      for (int r = 0; r < 4; r++)
        out[(size_t)(rbase + r) * D + c] = acc[m][n][r];
    }
  }
}

extern "C" void kernel_launch(void* const* d_in, const int* in_sizes, int n_in,
                              void* d_out, int out_size, void* d_ws, size_t ws_size,
                              hipStream_t stream) {
  (void)in_sizes; (void)n_in; (void)out_size;
  const float* Qin = (const float*)d_in[0];
  const float* Kin = (const float*)d_in[1];
  const float* Vin = (const float*)d_in[2];
  const float* cq  = (const float*)d_in[3];
  const float* ck  = (const float*)d_in[4];
  const float* Wq  = (const float*)d_in[5];
  const float* Wk  = (const float*)d_in[6];
  const float* Wv  = (const float*)d_in[7];
  const float* Wo  = (const float*)d_in[8];
  float* out = (float*)d_out;

  const size_t per = (size_t)NB * H * L * DH;  // 3,145,728 elems
  if (ws_size < 4 * per * sizeof(u16)) return;

  u16* q_ws  = (u16*)d_ws;
  u16* k_ws  = q_ws + per;
  u16* vt_ws = k_ws + per;
  u16* ao_ws = vt_ws + per;

  proj_qkv<<<dim3(8 * 24 * 3), dim3(256), 0, stream>>>(
      Qin, Kin, Vin, Wq, Wk, Wv, cq, ck, q_ws, k_ws, vt_ws);
  attn_fwd<<<dim3(32 * NB * H), dim3(256), 0, stream>>>(q_ws, k_ws, vt_ws, ao_ws);
  gemm_out<<<dim3(12 * 64), dim3(256), 0, stream>>>(ao_ws, Wo, out);
}

// Round 15
// 101.849 us; speedup vs baseline: 1.1377x; 1.1377x over previous
//
#include <hip/hip_runtime.h>
#include <stdint.h>

#define H 8
#define DH 96
#define L 2048
#define NB 2
#define D 768

typedef unsigned short u16;
typedef unsigned int u32;
typedef __attribute__((ext_vector_type(8))) __bf16 bf16x8;
typedef __attribute__((ext_vector_type(4))) float f32x4;
typedef __attribute__((ext_vector_type(4))) u32 u32x4;
typedef __attribute__((ext_vector_type(2))) u32 u32x2;
typedef __attribute__((ext_vector_type(4))) u16 u16x4;

// softmax scale folded with log2(e): 96^-0.5 * 1.4426950408889634
#define QSCALE 0.14724444f

static __device__ __forceinline__ u16 f2bf(float f) {
  union { __bf16 h; u16 u; } v;
  v.h = (__bf16)f;
  return v.u;
}

static __device__ __forceinline__ bf16x8 cvt8r(f32x4 a, f32x4 b) {
  bf16x8 r;
  r[0] = (__bf16)a[0]; r[1] = (__bf16)a[1]; r[2] = (__bf16)a[2]; r[3] = (__bf16)a[3];
  r[4] = (__bf16)b[0]; r[5] = (__bf16)b[1]; r[6] = (__bf16)b[2]; r[7] = (__bf16)b[3];
  return r;
}

// ---------------------------------------------------------------------------
// Fused QKV projection + RoPE (z=0: Q, z=1: K, z=2: V->V^T)
// REGRIDDED: BM=64 x BN=192 tiles -> 64*4*3 = 768 blocks = EXACTLY 3/CU,
// one scheduling round, zero tail (was 576 @ 2/CU = full round + 64-block
// tail wasting ~45% of wall time). 4 waves as 2x2, wave-tile 32x96 (a full
// head -> RoPE pairs in-wave). 12 waves/CU of TLP. BK=32, r9-style loop:
// issue t+1 at top, compute, stage, ONE barrier. XCD swizzle groups the 4
// col-tiles of one (z,row-panel) on one XCD.
// ---------------------------------------------------------------------------
__global__ __launch_bounds__(256, 3)
void proj_qkv(const float* __restrict__ Qin, const float* __restrict__ Kin,
              const float* __restrict__ Vin,
              const float* __restrict__ Wq, const float* __restrict__ Wk,
              const float* __restrict__ Wv,
              const float* __restrict__ cq, const float* __restrict__ ck,
              u16* __restrict__ qo, u16* __restrict__ ko, u16* __restrict__ vo)
{
  __shared__ u16 a_lds[2][64 * 40];
  __shared__ u16 b_lds[2][192 * 40];
  const int tid = threadIdx.x;
  const int lane = tid & 63;
  const int w = tid >> 6;
  const int wr = w >> 1, wc = w & 1;
  const int fr = lane & 15;
  const int hi = lane >> 4;

  // swizzle decode: 768 = 8 xcd * (4 bx * 8 byp * 3 z)
  const int f = blockIdx.x;
  const int xcd = f & 7;
  const int g = f >> 3;          // 0..95
  const int bx = g & 3;
  const int h2 = g >> 2;         // 0..23
  const int byp = h2 & 7;
  const int z = h2 >> 3;
  const int by = xcd + 8 * byp;  // 0..63
  const int row0 = by * 64;
  const int col0 = bx * 192;

  const float* A = (z == 0) ? Qin : ((z == 1) ? Kin : Vin);
  const float* W = (z == 0) ? Wq : ((z == 1) ? Wk : Wv);

  // staging: A 64x32 (2 f32x4/thread), B 192x32 (6 f32x4/thread)
  const int arow = tid >> 2;
  const int acol = (tid & 3) * 8;
  const float* pA = A + (size_t)(row0 + arow) * D + acol;
  const float* pB0 = W + (size_t)(col0 + arow) * D + acol;
  const float* pB1 = pB0 + (size_t)64 * D;
  const float* pB2 = pB0 + (size_t)128 * D;

  f32x4 acc[2][6] = {};
  f32x4 Ra[2], Rb[6];

  auto issue = [&](int k) {
    Ra[0] = *(const f32x4*)(pA + k);
    Ra[1] = *(const f32x4*)(pA + k + 4);
    Rb[0] = *(const f32x4*)(pB0 + k);
    Rb[1] = *(const f32x4*)(pB0 + k + 4);
    Rb[2] = *(const f32x4*)(pB1 + k);
    Rb[3] = *(const f32x4*)(pB1 + k + 4);
    Rb[4] = *(const f32x4*)(pB2 + k);
    Rb[5] = *(const f32x4*)(pB2 + k + 4);
  };
  auto stage = [&](int bi) {
    *(bf16x8*)(&a_lds[bi][arow * 40 + acol]) = cvt8r(Ra[0], Ra[1]);
    *(bf16x8*)(&b_lds[bi][arow * 40 + acol]) = cvt8r(Rb[0], Rb[1]);
    *(bf16x8*)(&b_lds[bi][(arow + 64) * 40 + acol]) = cvt8r(Rb[2], Rb[3]);
    *(bf16x8*)(&b_lds[bi][(arow + 128) * 40 + acol]) = cvt8r(Rb[4], Rb[5]);
  };
  auto compute = [&](int bi) {
    bf16x8 af[2], bf[6];
#pragma unroll
    for (int m = 0; m < 2; m++)
      af[m] = *(const bf16x8*)(&a_lds[bi][(wr * 32 + m * 16 + fr) * 40 + hi * 8]);
#pragma unroll
    for (int n = 0; n < 6; n++)
      bf[n] = *(const bf16x8*)(&b_lds[bi][(wc * 96 + n * 16 + fr) * 40 + hi * 8]);
#pragma unroll
    for (int m = 0; m < 2; m++)
#pragma unroll
      for (int n = 0; n < 6; n++)
        acc[m][n] = __builtin_amdgcn_mfma_f32_16x16x32_bf16(af[m], bf[n], acc[m][n], 0, 0, 0);
  };

  issue(0);
  stage(0);
  __syncthreads();

  int cur = 0;
#pragma unroll 1
  for (int t = 0; t < 24; t++) {
    if (t + 1 < 24) issue((t + 1) * 32);  // slack = this step's compute
    compute(cur);
    if (t + 1 < 24) stage(cur ^ 1);       // buf last read at t-1 (prev barrier)
    __syncthreads();
    cur ^= 1;
  }

  // wave covers cols [col0 + wc*96, +96) = one full head: hh const per wave
  const int hh = (col0 + wc * 96) / DH;
  if (z == 2) {
#pragma unroll
    for (int m = 0; m < 2; m++) {
      int rbase = row0 + wr * 32 + m * 16 + hi * 4;
#pragma unroll
      for (int n = 0; n < 6; n++) {
        int dd = n * 16 + fr;
#pragma unroll
        for (int r = 0; r < 4; r++) {
          int row = rbase + r;
          int b = row >> 11, l = row & (L - 1);
          vo[((size_t)((b * H + hh) * DH + dd)) * L + l] = f2bf(acc[m][n][r]);
        }
      }
    }
  } else {
    // RoPE: pairs (n1, n1+1), n1 in {0,2,4}; axis = n1/2; j = fr.
    const float* coords = (z == 0) ? cq : ck;
    u16* outp = (z == 0) ? qo : ko;
    const float postscale = (z == 0) ? QSCALE : 1.0f;
    const float invf = exp2f(-(float)fr * 0.83048202372184058f);
#pragma unroll
    for (int m = 0; m < 2; m++) {
      int rbase = row0 + wr * 32 + m * 16 + hi * 4;
#pragma unroll
      for (int np = 0; np < 3; np++) {
        int n1 = np * 2;
        int dd1 = n1 * 16 + fr;
#pragma unroll
        for (int r = 0; r < 4; r++) {
          int row = rbase + r;
          int b = row >> 11, l = row & (L - 1);
          float coord = coords[((size_t)(b * L + l)) * 3 + np];
          float ang = coord * invf;
          float sn = __sinf(ang), cs = __cosf(ang);
          float x1 = acc[m][n1][r], x2 = acc[m][n1 + 1][r];
          size_t base = ((size_t)((b * H + hh) * L + l)) * DH;
          outp[base + dd1] = f2bf((x1 * cs - x2 * sn) * postscale);
          outp[base + dd1 + 16] = f2bf((x1 * sn + x2 * cs) * postscale);
        }
      }
    }
  }
}

// ---------------------------------------------------------------------------
// Flash attention: r9 structure (1-deep in-wave prefetch, dbuf LDS, ONE
// barrier/tile, defer-max, lane-local l) + XCD swizzle.  (unchanged)
// ---------------------------------------------------------------------------
#define KSTR 104
#define VSTR 72
#define NT   (L / 64)
__global__ __launch_bounds__(256, 2)
void attn_fwd(const u16* __restrict__ q_ws, const u16* __restrict__ k_ws,
              const u16* __restrict__ vt_ws, u16* __restrict__ ao)
{
  __shared__ u16 k_lds[2][64 * KSTR];
  __shared__ u16 vt_lds[2][96 * VSTR];
  const int tid = threadIdx.x;
  const int lane = tid & 63;
  const int w = tid >> 6;

  // swizzle: q-tiles of one bh share f%8 -> same XCD (K/V L2-resident)
  const int f = blockIdx.x;
  const int xr = f & 7;
  const int g = f >> 3;          // 0..63
  const int qx = g & 31;
  const int bh = xr + 8 * (g >> 5);
  const int q0 = qx * 64;

  const int fr = lane & 15;
  const int hi = lane >> 4;
  const int fko = hi * 8;

  // staging offsets (K natural; V^T columns sigma-permuted in 4-chunks)
  int kg_off[3], kl_off[3], vg_off[3], vl0_off[3], vl1_off[3];
#pragma unroll
  for (int it = 0; it < 3; it++) {
    int ch = tid + it * 256;
    int krow = ch / 12, koff = (ch % 12) * 8;
    kg_off[it] = krow * DH + koff;
    kl_off[it] = krow * KSTR + koff;
    int vrow = ch >> 3, vq = (ch & 7) * 2;
    vg_off[it] = vrow * L + vq * 4;
    int s0 = ((vq >> 3) << 5) | ((vq & 3) << 3) | (((vq >> 2) & 1) << 2);
    int vq1 = vq + 1;
    int s1 = ((vq1 >> 3) << 5) | ((vq1 & 3) << 3) | (((vq1 >> 2) & 1) << 2);
    vl0_off[it] = vrow * VSTR + s0;
    vl1_off[it] = vrow * VSTR + s1;
  }

  // Q fragments (B-operand: lane fr = q-row)
  bf16x8 qf[3];
  const u16* qbase = q_ws + ((size_t)bh * L + q0 + w * 16 + fr) * DH;
#pragma unroll
  for (int ks = 0; ks < 3; ks++)
    qf[ks] = *(const bf16x8*)(qbase + ks * 32 + fko);

  f32x4 o[6] = {};
  float m_r = -1e30f, l_r = 0.f;

  const u16* kbase = k_ws + (size_t)bh * L * DH;
  const u16* vtbase = vt_ws + (size_t)bh * DH * L;

  u32x4 kreg[3], vreg[3];
#pragma unroll
  for (int it = 0; it < 3; it++) {
    kreg[it] = *(const u32x4*)(kbase + kg_off[it]);
    vreg[it] = *(const u32x4*)(vtbase + vg_off[it]);
  }
#pragma unroll
  for (int it = 0; it < 3; it++) {
    *(u32x4*)(&k_lds[0][kl_off[it]]) = kreg[it];
    u32x2 lo = { vreg[it][0], vreg[it][1] };
    u32x2 hi2 = { vreg[it][2], vreg[it][3] };
    *(u32x2*)(&vt_lds[0][vl0_off[it]]) = lo;
    *(u32x2*)(&vt_lds[0][vl1_off[it]]) = hi2;
  }
  __syncthreads();

  int cur = 0;
  for (int t = 0; t < NT; t++) {
    if (t + 1 < NT) {  // in-wave prefetch; latency hides under compute
      const u16* kb = kbase + (size_t)(t + 1) * 64 * DH;
      const u16* vb = vtbase + (t + 1) * 64;
#pragma unroll
      for (int it = 0; it < 3; it++) {
        kreg[it] = *(const u32x4*)(kb + kg_off[it]);
        vreg[it] = *(const u32x4*)(vb + vg_off[it]);
      }
    }

    // S^T = K Q^T : lane fr = q, s[kf][reg] at k = kf*16+hi*4+reg
    f32x4 s[4] = {};
#pragma unroll
    for (int ks = 0; ks < 3; ks++)
#pragma unroll
      for (int kf = 0; kf < 4; kf++) {
        bf16x8 kfrag = *(const bf16x8*)(&k_lds[cur][(kf * 16 + fr) * KSTR + ks * 32 + fko]);
        s[kf] = __builtin_amdgcn_mfma_f32_16x16x32_bf16(kfrag, qf[ks], s[kf], 0, 0, 0);
      }

    // T13 defer-max
    float pmax = fmaxf(fmaxf(s[0][0], s[0][1]), fmaxf(s[0][2], s[0][3]));
#pragma unroll
    for (int kf = 1; kf < 4; kf++)
      pmax = fmaxf(pmax, fmaxf(fmaxf(s[kf][0], s[kf][1]), fmaxf(s[kf][2], s[kf][3])));
    if (!__all(pmax - m_r <= 8.0f)) {
      float mx = fmaxf(pmax, __shfl_xor(pmax, 16));
      mx = fmaxf(mx, __shfl_xor(mx, 32));
      float mn = fmaxf(m_r, mx);
      float alpha = exp2f(m_r - mn);
      m_r = mn;
      l_r *= alpha;
#pragma unroll
      for (int df = 0; df < 6; df++)
#pragma unroll
        for (int r = 0; r < 4; r++)
          o[df][r] *= alpha;
    }

    float p[4][4];
    float rs = 0.f;
#pragma unroll
    for (int kf = 0; kf < 4; kf++)
#pragma unroll
      for (int r = 0; r < 4; r++) {
        float pv = exp2f(s[kf][r] - m_r);
        p[kf][r] = pv;
        rs += pv;
      }
    l_r += rs;  // lane-local; reduced in epilogue

    bf16x8 pt[2];
#pragma unroll
    for (int ks = 0; ks < 2; ks++)
#pragma unroll
      for (int j = 0; j < 8; j++)
        pt[ks][j] = (__bf16)p[2 * ks + (j >> 2)][j & 3];

    // O^T += V P^T
#pragma unroll
    for (int ks = 0; ks < 2; ks++)
#pragma unroll
      for (int df = 0; df < 6; df++) {
        bf16x8 vfrag = *(const bf16x8*)(&vt_lds[cur][(df * 16 + fr) * VSTR + ks * 32 + fko]);
        o[df] = __builtin_amdgcn_mfma_f32_16x16x32_bf16(vfrag, pt[ks], o[df], 0, 0, 0);
      }

    if (t + 1 < NT) {  // write buf last read at t-1 (ordered by prev barrier)
#pragma unroll
      for (int it = 0; it < 3; it++) {
        *(u32x4*)(&k_lds[cur ^ 1][kl_off[it]]) = kreg[it];
        u32x2 lo = { vreg[it][0], vreg[it][1] };
        u32x2 hi2 = { vreg[it][2], vreg[it][3] };
        *(u32x2*)(&vt_lds[cur ^ 1][vl0_off[it]]) = lo;
        *(u32x2*)(&vt_lds[cur ^ 1][vl1_off[it]]) = hi2;
      }
      __syncthreads();
      cur ^= 1;
    }
  }

  // epilogue: reduce l across the 4 hi-lanes of each q-row, then store
  float l_tot = l_r + __shfl_xor(l_r, 16);
  l_tot += __shfl_xor(l_tot, 32);
  const int b = bh >> 3, hh = bh & 7;
  const int l = q0 + w * 16 + fr;
  const float inv = 1.f / l_tot;
  u16* aop = ao + ((size_t)(b * L + l)) * D + hh * DH + hi * 4;
#pragma unroll
  for (int df = 0; df < 6; df++) {
    u16x4 pk;
#pragma unroll
    for (int r = 0; r < 4; r++)
      pk[r] = f2bf(o[df][r] * inv);
    *(u16x4*)(aop + df * 16) = pk;
  }
}

// ---------------------------------------------------------------------------
// Output projection: out = AO @ Wo^T; 64x64 tiles, XCD swizzle, 2-deep
// prefetch + dbuf LDS, one barrier per K-step.  (unchanged)
// ---------------------------------------------------------------------------
__global__ __launch_bounds__(256, 2)
void gemm_out(const u16* __restrict__ A, const float* __restrict__ W,
              float* __restrict__ out)
{
  __shared__ u16 a_lds[2][64 * 40];
  __shared__ u16 b_lds[2][64 * 40];
  const int tid = threadIdx.x;
  const int lane = tid & 63;
  const int w = tid >> 6;
  const int wr = w >> 1, wc = w & 1;

  const int f = blockIdx.x;
  const int xr = f & 7;
  const int g = f >> 3;          // 0..95
  const int bx = g % 12;
  const int wq = g / 12;         // 0..7
  const int by = xr + 8 * wq;    // 0..63
  const int row0 = by * 64;
  const int col0 = bx * 64;

  f32x4 acc[2][2] = {};
  const int srow = tid >> 2;
  const int scol = (tid & 3) * 8;
  const u16* pA = A + (size_t)(row0 + srow) * D + scol;
  const float* pW = W + (size_t)(col0 + srow) * D + scol;
  const int fr = lane & 15;
  const int fk = (lane >> 4) * 8;

  auto issueG = [&](int k, u32x4* ra, f32x4* rb) {
    ra[0] = *(const u32x4*)(pA + k);
    rb[0] = *(const f32x4*)(pW + k);
    rb[1] = *(const f32x4*)(pW + k + 4);
  };
  auto writeG = [&](int bi, const u32x4* ra, const f32x4* rb) {
    *(u32x4*)(&a_lds[bi][srow * 40 + scol]) = ra[0];
    *(bf16x8*)(&b_lds[bi][srow * 40 + scol]) = cvt8r(rb[0], rb[1]);
  };
  auto computeG = [&](int bi) {
    bf16x8 af[2], bfr[2];
#pragma unroll
    for (int m = 0; m < 2; m++)
      af[m] = *(const bf16x8*)(&a_lds[bi][(wr * 32 + m * 16 + fr) * 40 + fk]);
#pragma unroll
    for (int n = 0; n < 2; n++)
      bfr[n] = *(const bf16x8*)(&b_lds[bi][(wc * 32 + n * 16 + fr) * 40 + fk]);
#pragma unroll
    for (int m = 0; m < 2; m++)
#pragma unroll
      for (int n = 0; n < 2; n++)
        acc[m][n] = __builtin_amdgcn_mfma_f32_16x16x32_bf16(af[m], bfr[n], acc[m][n], 0, 0, 0);
  };

  u32x4 raA[1], raB[1];
  f32x4 rbA[2], rbB[2];
  issueG(0, raB, rbB);
  writeG(0, raB, rbB);
  issueG(32, raA, rbA);
  __syncthreads();

  for (int k0 = 0; k0 < D; k0 += 64) {
    if (k0 + 64 < D) issueG(k0 + 64, raB, rbB);
    computeG(0);
    writeG(1, raA, rbA);
    __syncthreads();
    if (k0 + 96 < D) issueG(k0 + 96, raA, rbA);
    computeG(1);
    if (k0 + 64 < D) writeG(0, raB, rbB);
    __syncthreads();
  }

#pragma unroll
  for (int m = 0; m < 2; m++) {
    int rbase = row0 + wr * 32 + m * 16 + (lane >> 4) * 4;
#pragma unroll
    for (int n = 0; n < 2; n++) {
      int c = col0 + wc * 32 + n * 16 + fr;
#pragma unroll
      for (int r = 0; r < 4; r++)
        out[(size_t)(rbase + r) * D + c] = acc[m][n][r];
    }
  }
}

extern "C" void kernel_launch(void* const* d_in, const int* in_sizes, int n_in,
                              void* d_out, int out_size, void* d_ws, size_t ws_size,
                              hipStream_t stream) {
  (void)in_sizes; (void)n_in; (void)out_size;
  const float* Qin = (const float*)d_in[0];
  const float* Kin = (const float*)d_in[1];
  const float* Vin = (const float*)d_in[2];
  const float* cq  = (const float*)d_in[3];
  const float* ck  = (const float*)d_in[4];
  const float* Wq  = (const float*)d_in[5];
  const float* Wk  = (const float*)d_in[6];
  const float* Wv  = (const float*)d_in[7];
  const float* Wo  = (const float*)d_in[8];
  float* out = (float*)d_out;

  const size_t per = (size_t)NB * H * L * DH;  // 3,145,728 elems
  if (ws_size < 4 * per * sizeof(u16)) return;

  u16* q_ws  = (u16*)d_ws;
  u16* k_ws  = q_ws + per;
  u16* vt_ws = k_ws + per;
  u16* ao_ws = vt_ws + per;

  proj_qkv<<<dim3(768), dim3(256), 0, stream>>>(
      Qin, Kin, Vin, Wq, Wk, Wv, cq, ck, q_ws, k_ws, vt_ws);
  attn_fwd<<<dim3(32 * NB * H), dim3(256), 0, stream>>>(q_ws, k_ws, vt_ws, ao_ws);
  gemm_out<<<dim3(12 * 64), dim3(256), 0, stream>>>(ao_ws, Wo, out);
}